// Round 7
// baseline (692.437 us; speedup 1.0000x reference)
//
#include <hip/hip_runtime.h>
#include <hip/hip_bf16.h>
#include <stdint.h>

#define NNODES 50000
#define NEDGES 800000
#define HC 256

typedef unsigned short u16;
typedef __attribute__((ext_vector_type(8))) short bf16x8;
typedef __attribute__((ext_vector_type(4))) float f32x4;

__device__ __forceinline__ float b2f(u16 v) {
    return __uint_as_float(((unsigned)v) << 16);
}
__device__ __forceinline__ u16 f2b(float f) {
    unsigned u = __float_as_uint(f);
    u += 0x7fff + ((u >> 16) & 1);
    return (u16)(u >> 16);
}

// param table: W1,atts1,attd1,We1,atte1,b1,g1,be1,W2,atts2,attd2,We2,atte2,b2,g2,be2,Wout,bout
__device__ __constant__ int dPO[19] = {0,16384,16640,16896,20992,21248,21504,21760,22016,
                                       87552,87808,88064,92160,92416,92672,92928,93184,93440,93441};
static const int hPO[19] = {0,16384,16640,16896,20992,21248,21504,21760,22016,
                            87552,87808,88064,92160,92416,92672,92928,93184,93440,93441};
#define TOTP 93441

__global__ void zero_init(unsigned* __restrict__ p, long nwords) {
    long i = (long)blockIdx.x * blockDim.x + threadIdx.x;
    long stride = (long)gridDim.x * blockDim.x;
    for (; i < nwords; i += stride) p[i] = 0u;
}

// 1 = bf16 inputs, 0 = fp32 inputs
__global__ void detect_dtype(const unsigned* __restrict__ xbits, int* __restrict__ flag) {
    __shared__ int cnt;
    if (threadIdx.x == 0) cnt = 0;
    __syncthreads();
    int sane = 0;
    for (int i = threadIdx.x; i < 1024; i += 256) {
        unsigned lo = xbits[i] & 0xffffu;
        int e = (int)((lo >> 7) & 0xff);
        if (e >= 117 && e <= 133) sane++;
    }
    atomicAdd(&cnt, sane);
    __syncthreads();
    if (threadIdx.x == 0) *flag = (cnt >= 512) ? 1 : 0;
}

__global__ void cvt_bf16(const void* __restrict__ src, u16* __restrict__ dst, int n,
                         const int* __restrict__ flag) {
    int isbf16 = *flag;
    int i = blockIdx.x * 256 + threadIdx.x;
    int stride = gridDim.x * 256;
    if (isbf16) {
        const u16* s = (const u16*)src;
        for (; i < n; i += stride) dst[i] = s[i];
    } else {
        const float* s = (const float*)src;
        for (; i < n; i += stride) dst[i] = f2b(s[i]);
    }
}

struct Ptrs18 { const void* s[18]; };
__global__ void cvt_params(Ptrs18 p, u16* __restrict__ dst, const int* __restrict__ flag) {
    int i = blockIdx.x * 256 + threadIdx.x;
    if (i >= TOTP) return;
    int isbf16 = *flag;
    int idx = 0;
    #pragma unroll
    for (int j = 1; j < 18; j++) idx += (i >= dPO[j]) ? 1 : 0;
    int rel = i - dPO[idx];
    dst[i] = isbf16 ? ((const u16*)p.s[idx])[rel] : f2b(((const float*)p.s[idx])[rel]);
}

__global__ void proj_weight(const u16* __restrict__ W, const u16* __restrict__ att,
                            float* __restrict__ out, int R) {
    int i = blockIdx.x * 256 + threadIdx.x;
    if (i >= R * 4) return;
    int f = i >> 2, h = i & 3;
    float s = 0.f;
    for (int c = 0; c < 64; c++)
        s += b2f(W[f * 256 + h * 64 + c]) * b2f(att[h * 64 + c]);
    out[i] = s;
}

__global__ void proj_weight2(const u16* __restrict__ W, const u16* __restrict__ atta,
                             const u16* __restrict__ attb,
                             float* __restrict__ outa, float* __restrict__ outb, int R) {
    int i = blockIdx.x * 256 + threadIdx.x;
    if (i >= R * 4) return;
    int f = i >> 2, h = i & 3;
    float sa = 0.f, sb = 0.f;
    for (int c = 0; c < 64; c++) {
        float w = b2f(W[f * 256 + h * 64 + c]);
        sa += w * b2f(atta[h * 64 + c]);
        sb += w * b2f(attb[h * 64 + c]);
    }
    outa[i] = sa;
    outb[i] = sb;
}

// W[K][256] -> WT[256][K]
__global__ void transpose_w(const u16* __restrict__ W, u16* __restrict__ WT, int K) {
    int i = blockIdx.x * 256 + threadIdx.x;
    if (i >= K * 256) return;
    int k = i / 256, c = i % 256;
    WT[c * K + k] = W[i];
}

// ---------------- degree histogram ----------------
__global__ void edge_deg(const int* __restrict__ edst, int* __restrict__ deg) {
    int e = blockIdx.x * 256 + threadIdx.x;
    if (e >= NEDGES) return;
    atomicAdd(&deg[edst[e]], 1);
}

// ---------------- CSR scan ----------------
__global__ void block_sum(const int* __restrict__ deg, int* __restrict__ bsums, int n) {
    __shared__ int lds[256];
    int i = blockIdx.x * 256 + threadIdx.x;
    lds[threadIdx.x] = (i < n) ? deg[i] : 0;
    __syncthreads();
    for (int s = 128; s; s >>= 1) {
        if (threadIdx.x < s) lds[threadIdx.x] += lds[threadIdx.x + s];
        __syncthreads();
    }
    if (threadIdx.x == 0) bsums[blockIdx.x] = lds[0];
}

__global__ void scan_bsums(const int* __restrict__ bsums, int* __restrict__ boffs, int nb) {
    __shared__ int lds[256];
    int t = threadIdx.x;
    int v = (t < nb) ? bsums[t] : 0;
    lds[t] = v;
    __syncthreads();
    for (int s = 1; s < 256; s <<= 1) {
        int u = (t >= s) ? lds[t - s] : 0;
        __syncthreads();
        lds[t] += u;
        __syncthreads();
    }
    boffs[t] = lds[t] - v;  // exclusive
}

__global__ void write_offsets(const int* __restrict__ deg, const int* __restrict__ boffs,
                              int* __restrict__ off, int* __restrict__ cursor, int n) {
    __shared__ int lds[256];
    int t = threadIdx.x;
    int i = blockIdx.x * 256 + t;
    int v = (i < n) ? deg[i] : 0;
    lds[t] = v;
    __syncthreads();
    for (int s = 1; s < 256; s <<= 1) {
        int u = (t >= s) ? lds[t - s] : 0;
        __syncthreads();
        lds[t] += u;
        __syncthreads();
    }
    int exc = lds[t] - v + boffs[blockIdx.x];
    if (i < n) { off[i] = exc; cursor[i] = exc; }
}

// scatter only 4-byte indices (minimal write amplification)
__global__ void csr_fill(const int* __restrict__ edst, int* __restrict__ cursor,
                         int* __restrict__ edges) {
    int e = blockIdx.x * 256 + threadIdx.x;
    if (e >= NEDGES) return;
    int p = atomicAdd(&cursor[edst[e]], 1);
    edges[p] = e;
}

// ---------------- permute+project: gather eattr via CSR, write coalesced ----------------
__global__ __launch_bounds__(256) void permute_ae(
    const void* __restrict__ eattr_raw, const int* __restrict__ flag,
    const int* __restrict__ edges, const int* __restrict__ esrc,
    const float* __restrict__ ve1, const float* __restrict__ ve2,
    int* __restrict__ srcc, float* __restrict__ aec1, float* __restrict__ aec2) {
    int p = blockIdx.x * 256 + threadIdx.x;
    if (p >= NEDGES) return;
    int e = edges[p];
    float a[16];
    if (*flag) {
        const u16* s = (const u16*)eattr_raw + (long)e * 16;
        const uint4* q = (const uint4*)s;
        uint4 q0 = q[0], q1 = q[1];
        unsigned w0[8] = {q0.x, q0.y, q0.z, q0.w, q1.x, q1.y, q1.z, q1.w};
        #pragma unroll
        for (int j = 0; j < 8; j++) {
            a[2 * j] = b2f((u16)(w0[j] & 0xffff));
            a[2 * j + 1] = b2f((u16)(w0[j] >> 16));
        }
    } else {
        const float* s = (const float*)eattr_raw + (long)e * 16;
        #pragma unroll
        for (int j = 0; j < 16; j += 4) {
            float4 q = *(const float4*)(s + j);
            a[j] = q.x; a[j + 1] = q.y; a[j + 2] = q.z; a[j + 3] = q.w;
        }
    }
    float4 s1, s2;
    float* s1p = (float*)&s1;
    float* s2p = (float*)&s2;
    #pragma unroll
    for (int h = 0; h < 4; h++) {
        float t1 = 0.f, t2 = 0.f;
        #pragma unroll
        for (int f = 0; f < 16; f++) {
            t1 += a[f] * ve1[f * 4 + h];
            t2 += a[f] * ve2[f * 4 + h];
        }
        s1p[h] = t1;
        s2p[h] = t2;
    }
    srcc[p] = esrc[e];
    *(float4*)(aec1 + (long)p * 4) = s1;
    *(float4*)(aec2 + (long)p * 4) = s2;
}

// ---------------- MFMA GEMM: out[M][256] = A[M][K] @ W[K][256] via WT[256][K] --------
template <int K>
__global__ __launch_bounds__(256) void gemm_mfma(const u16* __restrict__ A,
                                                 const u16* __restrict__ WT,
                                                 u16* __restrict__ out) {
    int tid = threadIdx.x;
    int wave = tid >> 6, lane = tid & 63;
    int quad = lane >> 4, l15 = lane & 15;
    long row0 = (long)blockIdx.x * 16;
    const u16* Arow = A + (row0 + l15) * K + quad * 8;
    const u16* Wbase = WT + (long)(wave * 64 + l15) * K + quad * 8;
    f32x4 acc[4] = {};
    for (int kk = 0; kk < K; kk += 32) {
        bf16x8 av = *(const bf16x8*)(Arow + kk);
        #pragma unroll
        for (int nt = 0; nt < 4; nt++) {
            bf16x8 bv = *(const bf16x8*)(Wbase + (long)nt * 16 * K + kk);
            acc[nt] = __builtin_amdgcn_mfma_f32_16x16x32_bf16(av, bv, acc[nt], 0, 0, 0);
        }
    }
    u16* orow = out + row0 * HC;
    #pragma unroll
    for (int nt = 0; nt < 4; nt++) {
        #pragma unroll
        for (int j = 0; j < 4; j++) {
            int r = quad * 4 + j;
            int c = wave * 64 + nt * 16 + l15;
            orow[(long)r * HC + c] = f2b(acc[nt][j]);
        }
    }
}

// ---------------- a_s/a_d projection ----------------
template <int K>
__global__ __launch_bounds__(256) void proj_att(const u16* __restrict__ X,
                                                const float* __restrict__ us,
                                                const float* __restrict__ ud,
                                                float* __restrict__ as_, float* __restrict__ ad_) {
    int wid = (blockIdx.x * 256 + threadIdx.x) >> 6;
    int lane = threadIdx.x & 63;
    if (wid >= NNODES) return;
    float pas[4] = {0.f, 0.f, 0.f, 0.f}, pad[4] = {0.f, 0.f, 0.f, 0.f};
    const u16* row = X + (long)wid * K;
    for (int f = lane; f < K; f += 64) {
        float xv = b2f(row[f]);
        #pragma unroll
        for (int h = 0; h < 4; h++) {
            pas[h] += xv * us[f * 4 + h];
            pad[h] += xv * ud[f * 4 + h];
        }
    }
    #pragma unroll
    for (int h = 0; h < 4; h++) {
        for (int o = 32; o; o >>= 1) {
            pas[h] += __shfl_down(pas[h], o);
            pad[h] += __shfl_down(pad[h], o);
        }
    }
    if (lane == 0) {
        #pragma unroll
        for (int h = 0; h < 4; h++) {
            as_[wid * 4 + h] = pas[h];
            ad_[wid * 4 + h] = pad[h];
        }
    }
}

// ---------------- fused GAT attention ----------------
// phase 1: lanes = 16 edge-slots x 4 heads -> per-head m, s, sum_ae
// phase 2: per 16-edge chunk, weights computed once per (edge,head) and
//          broadcast via shuffle into the channel-gather (1 exp / lane / 16 edges)
__global__ __launch_bounds__(256) void gat_fused(
    const u16* __restrict__ xs, const float* __restrict__ as_, const float* __restrict__ ad_,
    const float* __restrict__ aec, const int* __restrict__ srcc,
    const int* __restrict__ off, const int* __restrict__ deg,
    const u16* __restrict__ bias, u16* __restrict__ out) {
    int wid = (blockIdx.x * 256 + threadIdx.x) >> 6;
    if (wid >= NNODES) return;
    int lane = threadIdx.x & 63;
    int d = wid;
    int st = off[d], dg = deg[d];

    // ---- phase 1: slot = lane>>2, h = lane&3 ----
    int slot = lane >> 2, h = lane & 3;
    float adv = ad_[d * 4 + h];
    float m = -1e30f, s = 0.f, sae = 0.f;
    for (int base = 0; base < dg; base += 16) {
        int i = base + slot;
        float lg = -1e30f, aev = 0.f, w = 0.f;
        if (i < dg) {
            int p = st + i;
            int src = srcc[p];
            aev = aec[(long)p * 4 + h];
            float t = as_[src * 4 + h] + adv + aev;
            lg = (t > 0.f) ? t : 0.2f * t;
        }
        sae += aev;
        float mn = fmaxf(m, lg);
        if (i < dg) w = __expf(lg - mn);
        s = s * __expf(m - mn) + w;
        m = mn;
    }
    #pragma unroll
    for (int o = 4; o < 64; o <<= 1) {
        float mo = __shfl_xor(m, o), so = __shfl_xor(s, o), ao = __shfl_xor(sae, o);
        float mn = fmaxf(m, mo);
        s = s * __expf(m - mn) + so * __expf(mo - mn);
        m = mn;
        sae += ao;
    }
    float invs, wself;
    {
        float asv = as_[d * 4 + h];
        float l0 = asv + adv + sae / fmaxf((float)dg, 1.f);
        l0 = (l0 > 0.f) ? l0 : 0.2f * l0;
        float mn = fmaxf(m, l0);
        s = s * __expf(m - mn) + __expf(l0 - mn);
        m = mn;
        invs = 1.f / s;
        wself = __expf(l0 - mn) * invs;
    }

    // ---- phase 2: h2 = lane>>4 channel block; lane&15 = edge slot for step A ----
    int h2 = lane >> 4;
    float m2   = __shfl(m, h2);      // lane h2 holds head h2 (slot 0)
    float is2  = __shfl(invs, h2);
    float ws2  = __shfl(wself, h2);
    float adv2 = __shfl(adv, h2);
    int cb = lane * 4;
    float a0, a1, a2, a3;
    {
        uint2 v = *(const uint2*)(xs + (long)d * HC + cb);
        a0 = ws2 * b2f((u16)(v.x & 0xffff));
        a1 = ws2 * b2f((u16)(v.x >> 16));
        a2 = ws2 * b2f((u16)(v.y & 0xffff));
        a3 = ws2 * b2f((u16)(v.y >> 16));
    }
    int slot16 = lane & 15;
    int lhi = lane & 48;
    for (int base = 0; base < dg; base += 16) {
        int cnt = min(16, dg - base);
        // step A: weight for (edge=base+slot16, head=h2), computed once
        float wv = 0.f;
        int srcl = 0;
        if (slot16 < cnt) {
            int p = st + base + slot16;
            srcl = srcc[p];
            float aev = aec[(long)p * 4 + h2];
            float t = as_[srcl * 4 + h2] + adv2 + aev;
            t = (t > 0.f) ? t : 0.2f * t;
            wv = __expf(t - m2) * is2;
        }
        // step B: broadcast + gather, 4-wide for MLP
        int j = 0;
        for (; j + 4 <= cnt; j += 4) {
            float w0 = __shfl(wv, lhi | j);
            float w1 = __shfl(wv, lhi | (j + 1));
            float w2 = __shfl(wv, lhi | (j + 2));
            float w3 = __shfl(wv, lhi | (j + 3));
            int s0 = __shfl(srcl, j);
            int s1 = __shfl(srcl, j + 1);
            int s2v = __shfl(srcl, j + 2);
            int s3 = __shfl(srcl, j + 3);
            uint2 v0 = *(const uint2*)(xs + (long)s0 * HC + cb);
            uint2 v1 = *(const uint2*)(xs + (long)s1 * HC + cb);
            uint2 v2 = *(const uint2*)(xs + (long)s2v * HC + cb);
            uint2 v3 = *(const uint2*)(xs + (long)s3 * HC + cb);
            a0 += w0 * b2f((u16)(v0.x & 0xffff)) + w1 * b2f((u16)(v1.x & 0xffff))
                + w2 * b2f((u16)(v2.x & 0xffff)) + w3 * b2f((u16)(v3.x & 0xffff));
            a1 += w0 * b2f((u16)(v0.x >> 16)) + w1 * b2f((u16)(v1.x >> 16))
                + w2 * b2f((u16)(v2.x >> 16)) + w3 * b2f((u16)(v3.x >> 16));
            a2 += w0 * b2f((u16)(v0.y & 0xffff)) + w1 * b2f((u16)(v1.y & 0xffff))
                + w2 * b2f((u16)(v2.y & 0xffff)) + w3 * b2f((u16)(v3.y & 0xffff));
            a3 += w0 * b2f((u16)(v0.y >> 16)) + w1 * b2f((u16)(v1.y >> 16))
                + w2 * b2f((u16)(v2.y >> 16)) + w3 * b2f((u16)(v3.y >> 16));
        }
        for (; j < cnt; j++) {
            float w0 = __shfl(wv, lhi | j);
            int s0 = __shfl(srcl, j);
            uint2 v0 = *(const uint2*)(xs + (long)s0 * HC + cb);
            a0 += w0 * b2f((u16)(v0.x & 0xffff));
            a1 += w0 * b2f((u16)(v0.x >> 16));
            a2 += w0 * b2f((u16)(v0.y & 0xffff));
            a3 += w0 * b2f((u16)(v0.y >> 16));
        }
    }
    u16 o0 = f2b(a0 + b2f(bias[cb + 0]));
    u16 o1 = f2b(a1 + b2f(bias[cb + 1]));
    u16 o2 = f2b(a2 + b2f(bias[cb + 2]));
    u16 o3 = f2b(a3 + b2f(bias[cb + 3]));
    uint2 ov;
    ov.x = (unsigned)o0 | ((unsigned)o1 << 16);
    ov.y = (unsigned)o2 | ((unsigned)o3 << 16);
    *(uint2*)(out + (long)d * HC + cb) = ov;
}

// ---------------- BatchNorm (batch stats) + ReLU ----------------
__global__ void bn_stats(const u16* __restrict__ h, float* __restrict__ stats) {
    int c = threadIdx.x;
    float s = 0.f, q = 0.f;
    for (int r = blockIdx.x; r < NNODES; r += gridDim.x) {
        float v = b2f(h[(long)r * HC + c]);
        s += v;
        q += v * v;
    }
    atomicAdd(&stats[c], s);
    atomicAdd(&stats[256 + c], q);
}

__global__ void bn_apply(u16* __restrict__ h, const float* __restrict__ stats,
                         const u16* __restrict__ g, const u16* __restrict__ be) {
    long i = (long)blockIdx.x * 256 + threadIdx.x;
    if (i >= (long)NNODES * HC) return;
    int c = (int)(i & 255);
    float mu = stats[c] * (1.0f / NNODES);
    float var = stats[256 + c] * (1.0f / NNODES) - mu * mu;
    var = fmaxf(var, 0.f);
    float rs = rsqrtf(var + 1e-5f);
    float v = b2f(h[i]);
    float y = b2f(g[c]) * (v - mu) * rs + b2f(be[c]);
    h[i] = f2b(fmaxf(y, 0.f));
}

// ---------------- output head ----------------
__global__ __launch_bounds__(256) void out_head(const u16* __restrict__ h,
                                                const u16* __restrict__ wout,
                                                const u16* __restrict__ bout,
                                                void* __restrict__ y,
                                                const int* __restrict__ flag) {
    int wid = (blockIdx.x * 256 + threadIdx.x) >> 6;
    int lane = threadIdx.x & 63;
    if (wid >= NNODES) return;
    const u16* r = h + (long)wid * HC + lane * 4;
    float p = b2f(r[0]) * b2f(wout[lane * 4 + 0]) + b2f(r[1]) * b2f(wout[lane * 4 + 1]) +
              b2f(r[2]) * b2f(wout[lane * 4 + 2]) + b2f(r[3]) * b2f(wout[lane * 4 + 3]);
    for (int o = 32; o; o >>= 1) p += __shfl_down(p, o);
    if (lane == 0) {
        float v = p + b2f(bout[0]);
        if (*flag) ((u16*)y)[wid] = f2b(v);
        else       ((float*)y)[wid] = v;
    }
}

extern "C" void kernel_launch(void* const* d_in, const int* in_sizes, int n_in,
                              void* d_out, int out_size, void* d_ws, size_t ws_size,
                              hipStream_t stream) {
    (void)in_sizes; (void)n_in; (void)out_size; (void)ws_size;
    const void* x_raw     = d_in[0];
    const int*  esrc      = (const int*)d_in[1];
    const int*  edst      = (const int*)d_in[2];
    const void* eattr_raw = d_in[3];

    char* ws = (char*)d_ws;
    size_t o = 0;
    auto alloc = [&](size_t bytes) -> char* {
        o = (o + 255) & ~(size_t)255;
        char* p = ws + o;
        o += bytes;
        return p;
    };
    int* dflag = (int*)alloc(256);
    u16* xb   = (u16*)alloc((size_t)NNODES * 64 * 2);
    u16* pall = (u16*)alloc((size_t)TOTP * 2);
    u16 *W1b = pall + hPO[0], *atts1b = pall + hPO[1], *attd1b = pall + hPO[2],
        *We1b = pall + hPO[3], *atte1b = pall + hPO[4], *b1b = pall + hPO[5],
        *g1b = pall + hPO[6], *be1b = pall + hPO[7], *W2b = pall + hPO[8],
        *atts2b = pall + hPO[9], *attd2b = pall + hPO[10], *We2b = pall + hPO[11],
        *atte2b = pall + hPO[12], *b2b = pall + hPO[13], *g2b = pall + hPO[14],
        *be2b = pall + hPO[15], *Woutb = pall + hPO[16], *boutb = pall + hPO[17];
    u16* WT1 = (u16*)alloc(256 * 64 * 2);
    u16* WT2 = (u16*)alloc(256 * 256 * 2);
    float* ve1 = (float*)alloc(64 * 4);
    float* ve2 = (float*)alloc(64 * 4);
    float* us1 = (float*)alloc(256 * 4);
    float* ud1 = (float*)alloc(256 * 4);
    float* us2 = (float*)alloc(1024 * 4);
    float* ud2 = (float*)alloc(1024 * 4);
    // zero zone: deg + stats
    int* deg = (int*)alloc((size_t)NNODES * 4);
    float* stats1 = (float*)alloc(512 * 4);
    float* stats2 = (float*)alloc(512 * 4);
    size_t zero_end = o;
    size_t zero_begin = (size_t)((char*)deg - ws);
    // rest
    int* off = (int*)alloc((size_t)NNODES * 4);
    int* cursor = (int*)alloc((size_t)NNODES * 4);
    int* bsums = (int*)alloc(256 * 4);
    int* boffs = (int*)alloc(256 * 4);
    int* edges = (int*)alloc((size_t)NEDGES * 4);
    int* srcc = (int*)alloc((size_t)NEDGES * 4);
    float* aec1 = (float*)alloc((size_t)NEDGES * 16);
    float* aec2 = (float*)alloc((size_t)NEDGES * 16);
    float* as_ = (float*)alloc((size_t)NNODES * 16);
    float* ad_ = (float*)alloc((size_t)NNODES * 16);
    u16* bufA = (u16*)alloc((size_t)NNODES * HC * 2);  // xs1, then xs2
    u16* bufB = (u16*)alloc((size_t)NNODES * HC * 2);  // h1, then h2

    long zwords = (long)((zero_end - zero_begin) / 4);
    zero_init<<<128, 256, 0, stream>>>((unsigned*)(ws + zero_begin), zwords);
    detect_dtype<<<1, 256, 0, stream>>>((const unsigned*)x_raw, dflag);

    cvt_bf16<<<2048, 256, 0, stream>>>(x_raw, xb, NNODES * 64, dflag);
    Ptrs18 pp;
    for (int i = 0; i < 18; i++) pp.s[i] = d_in[4 + i];
    cvt_params<<<(TOTP + 255) / 256, 256, 0, stream>>>(pp, pall, dflag);

    transpose_w<<<64, 256, 0, stream>>>(W1b, WT1, 64);
    transpose_w<<<256, 256, 0, stream>>>(W2b, WT2, 256);
    proj_weight<<<1, 256, 0, stream>>>(We1b, atte1b, ve1, 16);
    proj_weight<<<1, 256, 0, stream>>>(We2b, atte2b, ve2, 16);
    proj_weight2<<<1, 256, 0, stream>>>(W1b, atts1b, attd1b, us1, ud1, 64);
    proj_weight2<<<4, 256, 0, stream>>>(W2b, atts2b, attd2b, us2, ud2, 256);

    int eblocks = (NEDGES + 255) / 256;
    int nb = (NNODES + 255) / 256;  // 196
    edge_deg<<<eblocks, 256, 0, stream>>>(edst, deg);
    block_sum<<<nb, 256, 0, stream>>>(deg, bsums, NNODES);
    scan_bsums<<<1, 256, 0, stream>>>(bsums, boffs, nb);
    write_offsets<<<nb, 256, 0, stream>>>(deg, boffs, off, cursor, NNODES);
    csr_fill<<<eblocks, 256, 0, stream>>>(edst, cursor, edges);
    permute_ae<<<eblocks, 256, 0, stream>>>(eattr_raw, dflag, edges, esrc, ve1, ve2,
                                            srcc, aec1, aec2);

    int mtiles = NNODES / 16;                 // 3125
    int wblocks = (NNODES * 64 + 255) / 256;  // 12500

    // layer 1 (xb: K=64)
    gemm_mfma<64><<<mtiles, 256, 0, stream>>>(xb, WT1, bufA);
    proj_att<64><<<wblocks, 256, 0, stream>>>(xb, us1, ud1, as_, ad_);
    gat_fused<<<wblocks, 256, 0, stream>>>(bufA, as_, ad_, aec1, srcc, off, deg, b1b, bufB);
    bn_stats<<<256, 256, 0, stream>>>(bufB, stats1);
    bn_apply<<<(NNODES * HC + 255) / 256, 256, 0, stream>>>(bufB, stats1, g1b, be1b);

    // layer 2 (h1 = bufB: K=256)
    gemm_mfma<256><<<mtiles, 256, 0, stream>>>(bufB, WT2, bufA);
    proj_att<256><<<wblocks, 256, 0, stream>>>(bufB, us2, ud2, as_, ad_);
    gat_fused<<<wblocks, 256, 0, stream>>>(bufA, as_, ad_, aec2, srcc, off, deg, b2b, bufB);
    bn_stats<<<256, 256, 0, stream>>>(bufB, stats2);
    bn_apply<<<(NNODES * HC + 255) / 256, 256, 0, stream>>>(bufB, stats2, g2b, be2b);

    out_head<<<wblocks, 256, 0, stream>>>(bufB, Woutb, boutb, d_out, dflag);
}

// Round 8
// 623.953 us; speedup vs baseline: 1.1098x; 1.1098x over previous
//
#include <hip/hip_runtime.h>
#include <hip/hip_bf16.h>
#include <stdint.h>

#define NNODES 50000
#define NEDGES 800000
#define HC 256

typedef unsigned short u16;
typedef __attribute__((ext_vector_type(8))) short bf16x8;
typedef __attribute__((ext_vector_type(4))) float f32x4;

__device__ __forceinline__ float b2f(u16 v) {
    return __uint_as_float(((unsigned)v) << 16);
}
__device__ __forceinline__ u16 f2b(float f) {
    unsigned u = __float_as_uint(f);
    u += 0x7fff + ((u >> 16) & 1);
    return (u16)(u >> 16);
}

// param table: W1,atts1,attd1,We1,atte1,b1,g1,be1,W2,atts2,attd2,We2,atte2,b2,g2,be2,Wout,bout
__device__ __constant__ int dPO[19] = {0,16384,16640,16896,20992,21248,21504,21760,22016,
                                       87552,87808,88064,92160,92416,92672,92928,93184,93440,93441};
static const int hPO[19] = {0,16384,16640,16896,20992,21248,21504,21760,22016,
                            87552,87808,88064,92160,92416,92672,92928,93184,93440,93441};
#define TOTP 93441

__global__ void zero_init(unsigned* __restrict__ p, long nwords) {
    long i = (long)blockIdx.x * blockDim.x + threadIdx.x;
    long stride = (long)gridDim.x * blockDim.x;
    for (; i < nwords; i += stride) p[i] = 0u;
}

// 1 = bf16 inputs, 0 = fp32 inputs
__global__ void detect_dtype(const unsigned* __restrict__ xbits, int* __restrict__ flag) {
    __shared__ int cnt;
    if (threadIdx.x == 0) cnt = 0;
    __syncthreads();
    int sane = 0;
    for (int i = threadIdx.x; i < 1024; i += 256) {
        unsigned lo = xbits[i] & 0xffffu;
        int e = (int)((lo >> 7) & 0xff);
        if (e >= 117 && e <= 133) sane++;
    }
    atomicAdd(&cnt, sane);
    __syncthreads();
    if (threadIdx.x == 0) *flag = (cnt >= 512) ? 1 : 0;
}

__global__ void cvt_bf16(const void* __restrict__ src, u16* __restrict__ dst, int n,
                         const int* __restrict__ flag) {
    int isbf16 = *flag;
    int i = blockIdx.x * 256 + threadIdx.x;
    int stride = gridDim.x * 256;
    if (isbf16) {
        const u16* s = (const u16*)src;
        for (; i < n; i += stride) dst[i] = s[i];
    } else {
        const float* s = (const float*)src;
        for (; i < n; i += stride) dst[i] = f2b(s[i]);
    }
}

struct Ptrs18 { const void* s[18]; };
__global__ void cvt_params(Ptrs18 p, u16* __restrict__ dst, const int* __restrict__ flag) {
    int i = blockIdx.x * 256 + threadIdx.x;
    if (i >= TOTP) return;
    int isbf16 = *flag;
    int idx = 0;
    #pragma unroll
    for (int j = 1; j < 18; j++) idx += (i >= dPO[j]) ? 1 : 0;
    int rel = i - dPO[idx];
    dst[i] = isbf16 ? ((const u16*)p.s[idx])[rel] : f2b(((const float*)p.s[idx])[rel]);
}

__global__ void proj_weight(const u16* __restrict__ W, const u16* __restrict__ att,
                            float* __restrict__ out, int R) {
    int i = blockIdx.x * 256 + threadIdx.x;
    if (i >= R * 4) return;
    int f = i >> 2, h = i & 3;
    float s = 0.f;
    for (int c = 0; c < 64; c++)
        s += b2f(W[f * 256 + h * 64 + c]) * b2f(att[h * 64 + c]);
    out[i] = s;
}

__global__ void proj_weight2(const u16* __restrict__ W, const u16* __restrict__ atta,
                             const u16* __restrict__ attb,
                             float* __restrict__ outa, float* __restrict__ outb, int R) {
    int i = blockIdx.x * 256 + threadIdx.x;
    if (i >= R * 4) return;
    int f = i >> 2, h = i & 3;
    float sa = 0.f, sb = 0.f;
    for (int c = 0; c < 64; c++) {
        float w = b2f(W[f * 256 + h * 64 + c]);
        sa += w * b2f(atta[h * 64 + c]);
        sb += w * b2f(attb[h * 64 + c]);
    }
    outa[i] = sa;
    outb[i] = sb;
}

// W[K][256] -> WT[256][K]
__global__ void transpose_w(const u16* __restrict__ W, u16* __restrict__ WT, int K) {
    int i = blockIdx.x * 256 + threadIdx.x;
    if (i >= K * 256) return;
    int k = i / 256, c = i % 256;
    WT[c * K + k] = W[i];
}

// ---------------- degree histogram ----------------
__global__ void edge_deg(const int* __restrict__ edst, int* __restrict__ deg) {
    int e = blockIdx.x * 256 + threadIdx.x;
    if (e >= NEDGES) return;
    atomicAdd(&deg[edst[e]], 1);
}

// ---------------- CSR scan ----------------
__global__ void block_sum(const int* __restrict__ deg, int* __restrict__ bsums, int n) {
    __shared__ int lds[256];
    int i = blockIdx.x * 256 + threadIdx.x;
    lds[threadIdx.x] = (i < n) ? deg[i] : 0;
    __syncthreads();
    for (int s = 128; s; s >>= 1) {
        if (threadIdx.x < s) lds[threadIdx.x] += lds[threadIdx.x + s];
        __syncthreads();
    }
    if (threadIdx.x == 0) bsums[blockIdx.x] = lds[0];
}

__global__ void scan_bsums(const int* __restrict__ bsums, int* __restrict__ boffs, int nb) {
    __shared__ int lds[256];
    int t = threadIdx.x;
    int v = (t < nb) ? bsums[t] : 0;
    lds[t] = v;
    __syncthreads();
    for (int s = 1; s < 256; s <<= 1) {
        int u = (t >= s) ? lds[t - s] : 0;
        __syncthreads();
        lds[t] += u;
        __syncthreads();
    }
    boffs[t] = lds[t] - v;  // exclusive
}

__global__ void write_offsets(const int* __restrict__ deg, const int* __restrict__ boffs,
                              int* __restrict__ off, int* __restrict__ cursor, int n) {
    __shared__ int lds[256];
    int t = threadIdx.x;
    int i = blockIdx.x * 256 + t;
    int v = (i < n) ? deg[i] : 0;
    lds[t] = v;
    __syncthreads();
    for (int s = 1; s < 256; s <<= 1) {
        int u = (t >= s) ? lds[t - s] : 0;
        __syncthreads();
        lds[t] += u;
        __syncthreads();
    }
    int exc = lds[t] - v + boffs[blockIdx.x];
    if (i < n) { off[i] = exc; cursor[i] = exc; }
}

// ---------------- edge stage: one 32B record per edge, scattered once ----------------
// rec[p*2+0] = {src, ae1_pk01, ae1_pk23, 0}; rec[p*2+1] = {src, ae2_pk01, ae2_pk23, 0}
__global__ __launch_bounds__(256) void edge_stage(
    const void* __restrict__ eattr_raw, const int* __restrict__ flag,
    const int* __restrict__ esrc, const int* __restrict__ edst,
    const float* __restrict__ ve1, const float* __restrict__ ve2,
    int* __restrict__ cursor, uint4* __restrict__ rec) {
    int e = blockIdx.x * 256 + threadIdx.x;
    if (e >= NEDGES) return;
    float a[16];
    if (*flag) {
        const u16* s = (const u16*)eattr_raw + (long)e * 16;
        const uint4* q = (const uint4*)s;
        uint4 q0 = q[0], q1 = q[1];
        unsigned w0[8] = {q0.x, q0.y, q0.z, q0.w, q1.x, q1.y, q1.z, q1.w};
        #pragma unroll
        for (int j = 0; j < 8; j++) {
            a[2 * j] = b2f((u16)(w0[j] & 0xffff));
            a[2 * j + 1] = b2f((u16)(w0[j] >> 16));
        }
    } else {
        const float* s = (const float*)eattr_raw + (long)e * 16;
        #pragma unroll
        for (int j = 0; j < 16; j += 4) {
            float4 q = *(const float4*)(s + j);
            a[j] = q.x; a[j + 1] = q.y; a[j + 2] = q.z; a[j + 3] = q.w;
        }
    }
    float s1[4], s2[4];
    #pragma unroll
    for (int h = 0; h < 4; h++) {
        float t1 = 0.f, t2 = 0.f;
        #pragma unroll
        for (int f = 0; f < 16; f++) {
            t1 += a[f] * ve1[f * 4 + h];
            t2 += a[f] * ve2[f * 4 + h];
        }
        s1[h] = t1;
        s2[h] = t2;
    }
    unsigned a1lo = (unsigned)f2b(s1[0]) | ((unsigned)f2b(s1[1]) << 16);
    unsigned a1hi = (unsigned)f2b(s1[2]) | ((unsigned)f2b(s1[3]) << 16);
    unsigned a2lo = (unsigned)f2b(s2[0]) | ((unsigned)f2b(s2[1]) << 16);
    unsigned a2hi = (unsigned)f2b(s2[2]) | ((unsigned)f2b(s2[3]) << 16);
    int d = edst[e];
    int p = atomicAdd(&cursor[d], 1);
    unsigned src = (unsigned)esrc[e];
    rec[(long)p * 2 + 0] = make_uint4(src, a1lo, a1hi, 0u);
    rec[(long)p * 2 + 1] = make_uint4(src, a2lo, a2hi, 0u);
}

// ---------------- MFMA GEMM: out[M][256] = A[M][K] @ W[K][256] via WT[256][K] --------
template <int K>
__global__ __launch_bounds__(256) void gemm_mfma(const u16* __restrict__ A,
                                                 const u16* __restrict__ WT,
                                                 u16* __restrict__ out) {
    int tid = threadIdx.x;
    int wave = tid >> 6, lane = tid & 63;
    int quad = lane >> 4, l15 = lane & 15;
    long row0 = (long)blockIdx.x * 16;
    const u16* Arow = A + (row0 + l15) * K + quad * 8;
    const u16* Wbase = WT + (long)(wave * 64 + l15) * K + quad * 8;
    f32x4 acc[4] = {};
    for (int kk = 0; kk < K; kk += 32) {
        bf16x8 av = *(const bf16x8*)(Arow + kk);
        #pragma unroll
        for (int nt = 0; nt < 4; nt++) {
            bf16x8 bv = *(const bf16x8*)(Wbase + (long)nt * 16 * K + kk);
            acc[nt] = __builtin_amdgcn_mfma_f32_16x16x32_bf16(av, bv, acc[nt], 0, 0, 0);
        }
    }
    u16* orow = out + row0 * HC;
    #pragma unroll
    for (int nt = 0; nt < 4; nt++) {
        #pragma unroll
        for (int j = 0; j < 4; j++) {
            int r = quad * 4 + j;
            int c = wave * 64 + nt * 16 + l15;
            orow[(long)r * HC + c] = f2b(acc[nt][j]);
        }
    }
}

// ---------------- a_s/a_d projection ----------------
template <int K>
__global__ __launch_bounds__(256) void proj_att(const u16* __restrict__ X,
                                                const float* __restrict__ us,
                                                const float* __restrict__ ud,
                                                float* __restrict__ as_, float* __restrict__ ad_) {
    int wid = (blockIdx.x * 256 + threadIdx.x) >> 6;
    int lane = threadIdx.x & 63;
    if (wid >= NNODES) return;
    float pas[4] = {0.f, 0.f, 0.f, 0.f}, pad[4] = {0.f, 0.f, 0.f, 0.f};
    const u16* row = X + (long)wid * K;
    for (int f = lane; f < K; f += 64) {
        float xv = b2f(row[f]);
        #pragma unroll
        for (int h = 0; h < 4; h++) {
            pas[h] += xv * us[f * 4 + h];
            pad[h] += xv * ud[f * 4 + h];
        }
    }
    #pragma unroll
    for (int h = 0; h < 4; h++) {
        for (int o = 32; o; o >>= 1) {
            pas[h] += __shfl_down(pas[h], o);
            pad[h] += __shfl_down(pad[h], o);
        }
    }
    if (lane == 0) {
        #pragma unroll
        for (int h = 0; h < 4; h++) {
            as_[wid * 4 + h] = pas[h];
            ad_[wid * 4 + h] = pad[h];
        }
    }
}

// ---------------- fused GAT attention, one wave per dst node ----------------
// fast path (deg<=64): phase1 computes logits -> LDS + online (m,s); finalize w in LDS;
// phase2 = pure weighted gather, 2 edges/iter (half-wave each), uint4 per lane.
__global__ __launch_bounds__(256) void gat_fused(
    const u16* __restrict__ xs, const float* __restrict__ as_, const float* __restrict__ ad_,
    const uint4* __restrict__ rec, int layer,
    const int* __restrict__ off, const int* __restrict__ deg,
    const u16* __restrict__ bias, u16* __restrict__ out) {
    __shared__ int s_lds[4][64];
    __shared__ float w_lds[4][64][4];
    int wid = (blockIdx.x * 256 + threadIdx.x) >> 6;
    if (wid >= NNODES) return;
    int wave = threadIdx.x >> 6;
    int lane = threadIdx.x & 63;
    int d = wid;
    int st = off[d], dg = deg[d];
    int slot = lane >> 2, h = lane & 3;
    float adv = ad_[d * 4 + h];
    float m = -1e30f, s = 0.f, sae = 0.f;

    if (dg <= 64) {
        // ---- phase 1 ----
        for (int i = slot; i < dg; i += 16) {
            uint4 r4 = rec[(long)(st + i) * 2 + layer];
            int src = (int)r4.x;
            unsigned wsel = (h & 2) ? r4.z : r4.y;
            float aev = b2f((u16)((h & 1) ? (wsel >> 16) : (wsel & 0xffffu)));
            float t = as_[src * 4 + h] + adv + aev;
            float lg = (t > 0.f) ? t : 0.2f * t;
            if (h == 0) s_lds[wave][i] = src;
            w_lds[wave][i][h] = lg;
            sae += aev;
            float mn = fmaxf(m, lg);
            s = s * __expf(m - mn) + __expf(lg - mn);
            m = mn;
        }
        #pragma unroll
        for (int o = 4; o < 64; o <<= 1) {
            float mo = __shfl_xor(m, o), so = __shfl_xor(s, o), ao = __shfl_xor(sae, o);
            float mn = fmaxf(m, mo);
            s = s * __expf(m - mn) + so * __expf(mo - mn);
            m = mn;
            sae += ao;
        }
        float invs, wself;
        {
            float asv = as_[d * 4 + h];
            float l0 = asv + adv + sae / fmaxf((float)dg, 1.f);
            l0 = (l0 > 0.f) ? l0 : 0.2f * l0;
            float mn = fmaxf(m, l0);
            s = s * __expf(m - mn) + __expf(l0 - mn);
            m = mn;
            invs = 1.f / s;
            wself = __expf(l0 - mn) * invs;
        }
        // finalize weights in LDS
        for (int i = slot; i < dg; i += 16)
            w_lds[wave][i][h] = __expf(w_lds[wave][i][h] - m) * invs;

        // ---- phase 2: 32 lanes x uint4 cover the row; 2 edges per iteration ----
        int cg = lane & 31, half = lane >> 5;
        int ch8 = cg * 8;
        int h2 = cg >> 3;
        float ws2 = __shfl(wself, h2);
        const u16* xbase = xs + ch8;
        float a0, a1, a2, a3, a4, a5, a6, a7;
        {
            uint4 v = *(const uint4*)(xbase + (long)d * HC);
            float wsf = half ? 0.f : ws2;
            a0 = wsf * b2f((u16)(v.x & 0xffffu)); a1 = wsf * b2f((u16)(v.x >> 16));
            a2 = wsf * b2f((u16)(v.y & 0xffffu)); a3 = wsf * b2f((u16)(v.y >> 16));
            a4 = wsf * b2f((u16)(v.z & 0xffffu)); a5 = wsf * b2f((u16)(v.z >> 16));
            a6 = wsf * b2f((u16)(v.w & 0xffffu)); a7 = wsf * b2f((u16)(v.w >> 16));
        }
        int i = half;
        for (; i + 2 < dg; i += 4) {
            float wA = w_lds[wave][i][h2];     int sA = s_lds[wave][i];
            float wB = w_lds[wave][i + 2][h2]; int sB = s_lds[wave][i + 2];
            uint4 vA = *(const uint4*)(xbase + (long)sA * HC);
            uint4 vB = *(const uint4*)(xbase + (long)sB * HC);
            a0 += wA * b2f((u16)(vA.x & 0xffffu)) + wB * b2f((u16)(vB.x & 0xffffu));
            a1 += wA * b2f((u16)(vA.x >> 16))     + wB * b2f((u16)(vB.x >> 16));
            a2 += wA * b2f((u16)(vA.y & 0xffffu)) + wB * b2f((u16)(vB.y & 0xffffu));
            a3 += wA * b2f((u16)(vA.y >> 16))     + wB * b2f((u16)(vB.y >> 16));
            a4 += wA * b2f((u16)(vA.z & 0xffffu)) + wB * b2f((u16)(vB.z & 0xffffu));
            a5 += wA * b2f((u16)(vA.z >> 16))     + wB * b2f((u16)(vB.z >> 16));
            a6 += wA * b2f((u16)(vA.w & 0xffffu)) + wB * b2f((u16)(vB.w & 0xffffu));
            a7 += wA * b2f((u16)(vA.w >> 16))     + wB * b2f((u16)(vB.w >> 16));
        }
        for (; i < dg; i += 2) {
            float wA = w_lds[wave][i][h2]; int sA = s_lds[wave][i];
            uint4 vA = *(const uint4*)(xbase + (long)sA * HC);
            a0 += wA * b2f((u16)(vA.x & 0xffffu)); a1 += wA * b2f((u16)(vA.x >> 16));
            a2 += wA * b2f((u16)(vA.y & 0xffffu)); a3 += wA * b2f((u16)(vA.y >> 16));
            a4 += wA * b2f((u16)(vA.z & 0xffffu)); a5 += wA * b2f((u16)(vA.z >> 16));
            a6 += wA * b2f((u16)(vA.w & 0xffffu)); a7 += wA * b2f((u16)(vA.w >> 16));
        }
        a0 += __shfl_xor(a0, 32); a1 += __shfl_xor(a1, 32);
        a2 += __shfl_xor(a2, 32); a3 += __shfl_xor(a3, 32);
        a4 += __shfl_xor(a4, 32); a5 += __shfl_xor(a5, 32);
        a6 += __shfl_xor(a6, 32); a7 += __shfl_xor(a7, 32);
        if (half == 0) {
            uint4 bv = *(const uint4*)(bias + ch8);
            a0 += b2f((u16)(bv.x & 0xffffu)); a1 += b2f((u16)(bv.x >> 16));
            a2 += b2f((u16)(bv.y & 0xffffu)); a3 += b2f((u16)(bv.y >> 16));
            a4 += b2f((u16)(bv.z & 0xffffu)); a5 += b2f((u16)(bv.z >> 16));
            a6 += b2f((u16)(bv.w & 0xffffu)); a7 += b2f((u16)(bv.w >> 16));
            uint4 ov;
            ov.x = (unsigned)f2b(a0) | ((unsigned)f2b(a1) << 16);
            ov.y = (unsigned)f2b(a2) | ((unsigned)f2b(a3) << 16);
            ov.z = (unsigned)f2b(a4) | ((unsigned)f2b(a5) << 16);
            ov.w = (unsigned)f2b(a6) | ((unsigned)f2b(a7) << 16);
            *(uint4*)(out + (long)d * HC + ch8) = ov;
        }
        return;
    }

    // ---------- fallback path (deg > 64): exact, round-7 style ----------
    for (int base = 0; base < dg; base += 16) {
        int i = base + slot;
        float lg = -1e30f, aev = 0.f, w = 0.f;
        if (i < dg) {
            uint4 r4 = rec[(long)(st + i) * 2 + layer];
            int src = (int)r4.x;
            unsigned wsel = (h & 2) ? r4.z : r4.y;
            aev = b2f((u16)((h & 1) ? (wsel >> 16) : (wsel & 0xffffu)));
            float t = as_[src * 4 + h] + adv + aev;
            lg = (t > 0.f) ? t : 0.2f * t;
        }
        sae += aev;
        float mn = fmaxf(m, lg);
        if (i < dg) w = __expf(lg - mn);
        s = s * __expf(m - mn) + w;
        m = mn;
    }
    #pragma unroll
    for (int o = 4; o < 64; o <<= 1) {
        float mo = __shfl_xor(m, o), so = __shfl_xor(s, o), ao = __shfl_xor(sae, o);
        float mn = fmaxf(m, mo);
        s = s * __expf(m - mn) + so * __expf(mo - mn);
        m = mn;
        sae += ao;
    }
    float invs, wself;
    {
        float asv = as_[d * 4 + h];
        float l0 = asv + adv + sae / fmaxf((float)dg, 1.f);
        l0 = (l0 > 0.f) ? l0 : 0.2f * l0;
        float mn = fmaxf(m, l0);
        s = s * __expf(m - mn) + __expf(l0 - mn);
        m = mn;
        invs = 1.f / s;
        wself = __expf(l0 - mn) * invs;
    }
    int h2 = lane >> 4;
    float m2 = __shfl(m, h2);
    float is2 = __shfl(invs, h2);
    float ws2 = __shfl(wself, h2);
    float adv2 = __shfl(adv, h2);
    int cb = lane * 4;
    float a0, a1, a2, a3;
    {
        uint2 v = *(const uint2*)(xs + (long)d * HC + cb);
        a0 = ws2 * b2f((u16)(v.x & 0xffffu)); a1 = ws2 * b2f((u16)(v.x >> 16));
        a2 = ws2 * b2f((u16)(v.y & 0xffffu)); a3 = ws2 * b2f((u16)(v.y >> 16));
    }
    int slot16 = lane & 15;
    int lhi = lane & 48;
    for (int base = 0; base < dg; base += 16) {
        int cnt = min(16, dg - base);
        float wv = 0.f;
        int srcl = 0;
        if (slot16 < cnt) {
            uint4 r4 = rec[(long)(st + base + slot16) * 2 + layer];
            srcl = (int)r4.x;
            unsigned wsel = (h2 & 2) ? r4.z : r4.y;
            float aev = b2f((u16)((h2 & 1) ? (wsel >> 16) : (wsel & 0xffffu)));
            float t = as_[srcl * 4 + h2] + adv2 + aev;
            t = (t > 0.f) ? t : 0.2f * t;
            wv = __expf(t - m2) * is2;
        }
        for (int j = 0; j < cnt; j++) {
            float w0 = __shfl(wv, lhi | j);
            int s0 = __shfl(srcl, j);
            uint2 v0 = *(const uint2*)(xs + (long)s0 * HC + cb);
            a0 += w0 * b2f((u16)(v0.x & 0xffffu));
            a1 += w0 * b2f((u16)(v0.x >> 16));
            a2 += w0 * b2f((u16)(v0.y & 0xffffu));
            a3 += w0 * b2f((u16)(v0.y >> 16));
        }
    }
    u16 o0 = f2b(a0 + b2f(bias[cb + 0]));
    u16 o1 = f2b(a1 + b2f(bias[cb + 1]));
    u16 o2 = f2b(a2 + b2f(bias[cb + 2]));
    u16 o3 = f2b(a3 + b2f(bias[cb + 3]));
    uint2 ov;
    ov.x = (unsigned)o0 | ((unsigned)o1 << 16);
    ov.y = (unsigned)o2 | ((unsigned)o3 << 16);
    *(uint2*)(out + (long)d * HC + cb) = ov;
}

// ---------------- BatchNorm (batch stats) + ReLU ----------------
__global__ void bn_stats(const u16* __restrict__ h, float* __restrict__ stats) {
    int c = threadIdx.x;
    float s = 0.f, q = 0.f;
    for (int r = blockIdx.x; r < NNODES; r += gridDim.x) {
        float v = b2f(h[(long)r * HC + c]);
        s += v;
        q += v * v;
    }
    atomicAdd(&stats[c], s);
    atomicAdd(&stats[256 + c], q);
}

__global__ void bn_apply(u16* __restrict__ h, const float* __restrict__ stats,
                         const u16* __restrict__ g, const u16* __restrict__ be) {
    long i = (long)blockIdx.x * 256 + threadIdx.x;
    if (i >= (long)NNODES * HC) return;
    int c = (int)(i & 255);
    float mu = stats[c] * (1.0f / NNODES);
    float var = stats[256 + c] * (1.0f / NNODES) - mu * mu;
    var = fmaxf(var, 0.f);
    float rs = rsqrtf(var + 1e-5f);
    float v = b2f(h[i]);
    float y = b2f(g[c]) * (v - mu) * rs + b2f(be[c]);
    h[i] = f2b(fmaxf(y, 0.f));
}

// ---------------- output head ----------------
__global__ __launch_bounds__(256) void out_head(const u16* __restrict__ h,
                                                const u16* __restrict__ wout,
                                                const u16* __restrict__ bout,
                                                void* __restrict__ y,
                                                const int* __restrict__ flag) {
    int wid = (blockIdx.x * 256 + threadIdx.x) >> 6;
    int lane = threadIdx.x & 63;
    if (wid >= NNODES) return;
    const u16* r = h + (long)wid * HC + lane * 4;
    float p = b2f(r[0]) * b2f(wout[lane * 4 + 0]) + b2f(r[1]) * b2f(wout[lane * 4 + 1]) +
              b2f(r[2]) * b2f(wout[lane * 4 + 2]) + b2f(r[3]) * b2f(wout[lane * 4 + 3]);
    for (int o = 32; o; o >>= 1) p += __shfl_down(p, o);
    if (lane == 0) {
        float v = p + b2f(bout[0]);
        if (*flag) ((u16*)y)[wid] = f2b(v);
        else       ((float*)y)[wid] = v;
    }
}

extern "C" void kernel_launch(void* const* d_in, const int* in_sizes, int n_in,
                              void* d_out, int out_size, void* d_ws, size_t ws_size,
                              hipStream_t stream) {
    (void)in_sizes; (void)n_in; (void)out_size; (void)ws_size;
    const void* x_raw     = d_in[0];
    const int*  esrc      = (const int*)d_in[1];
    const int*  edst      = (const int*)d_in[2];
    const void* eattr_raw = d_in[3];

    char* ws = (char*)d_ws;
    size_t o = 0;
    auto alloc = [&](size_t bytes) -> char* {
        o = (o + 255) & ~(size_t)255;
        char* p = ws + o;
        o += bytes;
        return p;
    };
    int* dflag = (int*)alloc(256);
    u16* xb   = (u16*)alloc((size_t)NNODES * 64 * 2);
    u16* pall = (u16*)alloc((size_t)TOTP * 2);
    u16 *W1b = pall + hPO[0], *atts1b = pall + hPO[1], *attd1b = pall + hPO[2],
        *We1b = pall + hPO[3], *atte1b = pall + hPO[4], *b1b = pall + hPO[5],
        *g1b = pall + hPO[6], *be1b = pall + hPO[7], *W2b = pall + hPO[8],
        *atts2b = pall + hPO[9], *attd2b = pall + hPO[10], *We2b = pall + hPO[11],
        *atte2b = pall + hPO[12], *b2b = pall + hPO[13], *g2b = pall + hPO[14],
        *be2b = pall + hPO[15], *Woutb = pall + hPO[16], *boutb = pall + hPO[17];
    u16* WT1 = (u16*)alloc(256 * 64 * 2);
    u16* WT2 = (u16*)alloc(256 * 256 * 2);
    float* ve1 = (float*)alloc(64 * 4);
    float* ve2 = (float*)alloc(64 * 4);
    float* us1 = (float*)alloc(256 * 4);
    float* ud1 = (float*)alloc(256 * 4);
    float* us2 = (float*)alloc(1024 * 4);
    float* ud2 = (float*)alloc(1024 * 4);
    // zero zone: deg + stats
    int* deg = (int*)alloc((size_t)NNODES * 4);
    float* stats1 = (float*)alloc(512 * 4);
    float* stats2 = (float*)alloc(512 * 4);
    size_t zero_end = o;
    size_t zero_begin = (size_t)((char*)deg - ws);
    // rest
    int* off = (int*)alloc((size_t)NNODES * 4);
    int* cursor = (int*)alloc((size_t)NNODES * 4);
    int* bsums = (int*)alloc(256 * 4);
    int* boffs = (int*)alloc(256 * 4);
    uint4* rec = (uint4*)alloc((size_t)NEDGES * 32);
    float* as_ = (float*)alloc((size_t)NNODES * 16);
    float* ad_ = (float*)alloc((size_t)NNODES * 16);
    u16* bufA = (u16*)alloc((size_t)NNODES * HC * 2);  // xs1, then xs2
    u16* bufB = (u16*)alloc((size_t)NNODES * HC * 2);  // h1, then h2

    long zwords = (long)((zero_end - zero_begin) / 4);
    zero_init<<<128, 256, 0, stream>>>((unsigned*)(ws + zero_begin), zwords);
    detect_dtype<<<1, 256, 0, stream>>>((const unsigned*)x_raw, dflag);

    cvt_bf16<<<2048, 256, 0, stream>>>(x_raw, xb, NNODES * 64, dflag);
    Ptrs18 pp;
    for (int i = 0; i < 18; i++) pp.s[i] = d_in[4 + i];
    cvt_params<<<(TOTP + 255) / 256, 256, 0, stream>>>(pp, pall, dflag);

    transpose_w<<<64, 256, 0, stream>>>(W1b, WT1, 64);
    transpose_w<<<256, 256, 0, stream>>>(W2b, WT2, 256);
    proj_weight<<<1, 256, 0, stream>>>(We1b, atte1b, ve1, 16);
    proj_weight<<<1, 256, 0, stream>>>(We2b, atte2b, ve2, 16);
    proj_weight2<<<1, 256, 0, stream>>>(W1b, atts1b, attd1b, us1, ud1, 64);
    proj_weight2<<<4, 256, 0, stream>>>(W2b, atts2b, attd2b, us2, ud2, 256);

    int eblocks = (NEDGES + 255) / 256;
    int nb = (NNODES + 255) / 256;  // 196
    edge_deg<<<eblocks, 256, 0, stream>>>(edst, deg);
    block_sum<<<nb, 256, 0, stream>>>(deg, bsums, NNODES);
    scan_bsums<<<1, 256, 0, stream>>>(bsums, boffs, nb);
    write_offsets<<<nb, 256, 0, stream>>>(deg, boffs, off, cursor, NNODES);
    edge_stage<<<eblocks, 256, 0, stream>>>(eattr_raw, dflag, esrc, edst, ve1, ve2,
                                            cursor, rec);

    int mtiles = NNODES / 16;                 // 3125
    int wblocks = (NNODES * 64 + 255) / 256;  // 12500

    // layer 1 (xb: K=64)
    gemm_mfma<64><<<mtiles, 256, 0, stream>>>(xb, WT1, bufA);
    proj_att<64><<<wblocks, 256, 0, stream>>>(xb, us1, ud1, as_, ad_);
    gat_fused<<<wblocks, 256, 0, stream>>>(bufA, as_, ad_, rec, 0, off, deg, b1b, bufB);
    bn_stats<<<512, 256, 0, stream>>>(bufB, stats1);
    bn_apply<<<(NNODES * HC + 255) / 256, 256, 0, stream>>>(bufB, stats1, g1b, be1b);

    // layer 2 (h1 = bufB: K=256)
    gemm_mfma<256><<<mtiles, 256, 0, stream>>>(bufB, WT2, bufA);
    proj_att<256><<<wblocks, 256, 0, stream>>>(bufB, us2, ud2, as_, ad_);
    gat_fused<<<wblocks, 256, 0, stream>>>(bufA, as_, ad_, rec, 1, off, deg, b2b, bufB);
    bn_stats<<<512, 256, 0, stream>>>(bufB, stats2);
    bn_apply<<<(NNODES * HC + 255) / 256, 256, 0, stream>>>(bufB, stats2, g2b, be2b);

    out_head<<<wblocks, 256, 0, stream>>>(bufB, Woutb, boutb, d_out, dflag);
}

// Round 9
// 621.084 us; speedup vs baseline: 1.1149x; 1.0046x over previous
//
#include <hip/hip_runtime.h>
#include <hip/hip_bf16.h>
#include <stdint.h>

#define NNODES 50000
#define NEDGES 800000
#define HC 256

typedef unsigned short u16;
typedef __attribute__((ext_vector_type(8))) short bf16x8;
typedef __attribute__((ext_vector_type(4))) float f32x4;

__device__ __forceinline__ float b2f(u16 v) {
    return __uint_as_float(((unsigned)v) << 16);
}
__device__ __forceinline__ u16 f2b(float f) {
    unsigned u = __float_as_uint(f);
    u += 0x7fff + ((u >> 16) & 1);
    return (u16)(u >> 16);
}

// param table: W1,atts1,attd1,We1,atte1,b1,g1,be1,W2,atts2,attd2,We2,atte2,b2,g2,be2,Wout,bout
__device__ __constant__ int dPO[19] = {0,16384,16640,16896,20992,21248,21504,21760,22016,
                                       87552,87808,88064,92160,92416,92672,92928,93184,93440,93441};
static const int hPO[19] = {0,16384,16640,16896,20992,21248,21504,21760,22016,
                            87552,87808,88064,92160,92416,92672,92928,93184,93440,93441};
#define TOTP 93441

__global__ void zero_init(unsigned* __restrict__ p, long nwords) {
    long i = (long)blockIdx.x * blockDim.x + threadIdx.x;
    long stride = (long)gridDim.x * blockDim.x;
    for (; i < nwords; i += stride) p[i] = 0u;
}

// 1 = bf16 inputs, 0 = fp32 inputs
__global__ void detect_dtype(const unsigned* __restrict__ xbits, int* __restrict__ flag) {
    __shared__ int cnt;
    if (threadIdx.x == 0) cnt = 0;
    __syncthreads();
    int sane = 0;
    for (int i = threadIdx.x; i < 1024; i += 256) {
        unsigned lo = xbits[i] & 0xffffu;
        int e = (int)((lo >> 7) & 0xff);
        if (e >= 117 && e <= 133) sane++;
    }
    atomicAdd(&cnt, sane);
    __syncthreads();
    if (threadIdx.x == 0) *flag = (cnt >= 512) ? 1 : 0;
}

__global__ void cvt_bf16(const void* __restrict__ src, u16* __restrict__ dst, int n,
                         const int* __restrict__ flag) {
    int isbf16 = *flag;
    int i = blockIdx.x * 256 + threadIdx.x;
    int stride = gridDim.x * 256;
    if (isbf16) {
        const u16* s = (const u16*)src;
        for (; i < n; i += stride) dst[i] = s[i];
    } else {
        const float* s = (const float*)src;
        for (; i < n; i += stride) dst[i] = f2b(s[i]);
    }
}

struct Ptrs18 { const void* s[18]; };
__global__ void cvt_params(Ptrs18 p, u16* __restrict__ dst, const int* __restrict__ flag) {
    int i = blockIdx.x * 256 + threadIdx.x;
    if (i >= TOTP) return;
    int isbf16 = *flag;
    int idx = 0;
    #pragma unroll
    for (int j = 1; j < 18; j++) idx += (i >= dPO[j]) ? 1 : 0;
    int rel = i - dPO[idx];
    dst[i] = isbf16 ? ((const u16*)p.s[idx])[rel] : f2b(((const float*)p.s[idx])[rel]);
}

__global__ void proj_weight(const u16* __restrict__ W, const u16* __restrict__ att,
                            float* __restrict__ out, int R) {
    int i = blockIdx.x * 256 + threadIdx.x;
    if (i >= R * 4) return;
    int f = i >> 2, h = i & 3;
    float s = 0.f;
    for (int c = 0; c < 64; c++)
        s += b2f(W[f * 256 + h * 64 + c]) * b2f(att[h * 64 + c]);
    out[i] = s;
}

__global__ void proj_weight2(const u16* __restrict__ W, const u16* __restrict__ atta,
                             const u16* __restrict__ attb,
                             float* __restrict__ outa, float* __restrict__ outb, int R) {
    int i = blockIdx.x * 256 + threadIdx.x;
    if (i >= R * 4) return;
    int f = i >> 2, h = i & 3;
    float sa = 0.f, sb = 0.f;
    for (int c = 0; c < 64; c++) {
        float w = b2f(W[f * 256 + h * 64 + c]);
        sa += w * b2f(atta[h * 64 + c]);
        sb += w * b2f(attb[h * 64 + c]);
    }
    outa[i] = sa;
    outb[i] = sb;
}

// W[K][256] -> WT[256][K]
__global__ void transpose_w(const u16* __restrict__ W, u16* __restrict__ WT, int K) {
    int i = blockIdx.x * 256 + threadIdx.x;
    if (i >= K * 256) return;
    int k = i / 256, c = i % 256;
    WT[c * K + k] = W[i];
}

// ---------------- degree histogram ----------------
__global__ void edge_deg(const int* __restrict__ edst, int* __restrict__ deg) {
    int e = blockIdx.x * 256 + threadIdx.x;
    if (e >= NEDGES) return;
    atomicAdd(&deg[edst[e]], 1);
}

// ---------------- CSR scan ----------------
__global__ void block_sum(const int* __restrict__ deg, int* __restrict__ bsums, int n) {
    __shared__ int lds[256];
    int i = blockIdx.x * 256 + threadIdx.x;
    lds[threadIdx.x] = (i < n) ? deg[i] : 0;
    __syncthreads();
    for (int s = 128; s; s >>= 1) {
        if (threadIdx.x < s) lds[threadIdx.x] += lds[threadIdx.x + s];
        __syncthreads();
    }
    if (threadIdx.x == 0) bsums[blockIdx.x] = lds[0];
}

__global__ void scan_bsums(const int* __restrict__ bsums, int* __restrict__ boffs, int nb) {
    __shared__ int lds[256];
    int t = threadIdx.x;
    int v = (t < nb) ? bsums[t] : 0;
    lds[t] = v;
    __syncthreads();
    for (int s = 1; s < 256; s <<= 1) {
        int u = (t >= s) ? lds[t - s] : 0;
        __syncthreads();
        lds[t] += u;
        __syncthreads();
    }
    boffs[t] = lds[t] - v;  // exclusive
}

__global__ void write_offsets(const int* __restrict__ deg, const int* __restrict__ boffs,
                              int* __restrict__ off, int* __restrict__ cursor, int n) {
    __shared__ int lds[256];
    int t = threadIdx.x;
    int i = blockIdx.x * 256 + t;
    int v = (i < n) ? deg[i] : 0;
    lds[t] = v;
    __syncthreads();
    for (int s = 1; s < 256; s <<= 1) {
        int u = (t >= s) ? lds[t - s] : 0;
        __syncthreads();
        lds[t] += u;
        __syncthreads();
    }
    int exc = lds[t] - v + boffs[blockIdx.x];
    if (i < n) { off[i] = exc; cursor[i] = exc; }
}

// ---------------- edge stage: one 32B record per edge, scattered once ----------------
__global__ __launch_bounds__(256) void edge_stage(
    const void* __restrict__ eattr_raw, const int* __restrict__ flag,
    const int* __restrict__ esrc, const int* __restrict__ edst,
    const float* __restrict__ ve1, const float* __restrict__ ve2,
    int* __restrict__ cursor, uint4* __restrict__ rec) {
    int e = blockIdx.x * 256 + threadIdx.x;
    if (e >= NEDGES) return;
    float a[16];
    if (*flag) {
        const u16* s = (const u16*)eattr_raw + (long)e * 16;
        const uint4* q = (const uint4*)s;
        uint4 q0 = q[0], q1 = q[1];
        unsigned w0[8] = {q0.x, q0.y, q0.z, q0.w, q1.x, q1.y, q1.z, q1.w};
        #pragma unroll
        for (int j = 0; j < 8; j++) {
            a[2 * j] = b2f((u16)(w0[j] & 0xffff));
            a[2 * j + 1] = b2f((u16)(w0[j] >> 16));
        }
    } else {
        const float* s = (const float*)eattr_raw + (long)e * 16;
        #pragma unroll
        for (int j = 0; j < 16; j += 4) {
            float4 q = *(const float4*)(s + j);
            a[j] = q.x; a[j + 1] = q.y; a[j + 2] = q.z; a[j + 3] = q.w;
        }
    }
    float s1[4], s2[4];
    #pragma unroll
    for (int h = 0; h < 4; h++) {
        float t1 = 0.f, t2 = 0.f;
        #pragma unroll
        for (int f = 0; f < 16; f++) {
            t1 += a[f] * ve1[f * 4 + h];
            t2 += a[f] * ve2[f * 4 + h];
        }
        s1[h] = t1;
        s2[h] = t2;
    }
    unsigned a1lo = (unsigned)f2b(s1[0]) | ((unsigned)f2b(s1[1]) << 16);
    unsigned a1hi = (unsigned)f2b(s1[2]) | ((unsigned)f2b(s1[3]) << 16);
    unsigned a2lo = (unsigned)f2b(s2[0]) | ((unsigned)f2b(s2[1]) << 16);
    unsigned a2hi = (unsigned)f2b(s2[2]) | ((unsigned)f2b(s2[3]) << 16);
    int d = edst[e];
    int p = atomicAdd(&cursor[d], 1);
    unsigned src = (unsigned)esrc[e];
    rec[(long)p * 2 + 0] = make_uint4(src, a1lo, a1hi, 0u);
    rec[(long)p * 2 + 1] = make_uint4(src, a2lo, a2hi, 0u);
}

// ---------------- BN coefficient finalize: y = v*coef[c] + coef[256+c] ----------------
__global__ void bn_coef(const float* __restrict__ stats, const u16* __restrict__ g,
                        const u16* __restrict__ be, float* __restrict__ coef) {
    int c = threadIdx.x;  // 256
    float mu = stats[c] * (1.0f / NNODES);
    float var = stats[256 + c] * (1.0f / NNODES) - mu * mu;
    var = fmaxf(var, 0.f);
    float rs = rsqrtf(var + 1e-5f);
    float sc = b2f(g[c]) * rs;
    coef[c] = sc;
    coef[256 + c] = b2f(be[c]) - sc * mu;
}

// ---------------- MFMA GEMM (+optional fused BN+ReLU on A) ----------------
template <int K, bool BN>
__global__ __launch_bounds__(256) void gemm_mfma(const u16* __restrict__ A,
                                                 const u16* __restrict__ WT,
                                                 const float* __restrict__ coef,
                                                 u16* __restrict__ out) {
    int tid = threadIdx.x;
    int wave = tid >> 6, lane = tid & 63;
    int quad = lane >> 4, l15 = lane & 15;
    long row0 = (long)blockIdx.x * 16;
    const u16* Arow = A + (row0 + l15) * K + quad * 8;
    const u16* Wbase = WT + (long)(wave * 64 + l15) * K + quad * 8;
    f32x4 acc[4] = {};
    for (int kk = 0; kk < K; kk += 32) {
        bf16x8 av = *(const bf16x8*)(Arow + kk);
        if (BN) {
            int kb = kk + quad * 8;
            float4 sc0 = *(const float4*)(coef + kb);
            float4 sc1 = *(const float4*)(coef + kb + 4);
            float4 sh0 = *(const float4*)(coef + 256 + kb);
            float4 sh1 = *(const float4*)(coef + 256 + kb + 4);
            float scl[8] = {sc0.x, sc0.y, sc0.z, sc0.w, sc1.x, sc1.y, sc1.z, sc1.w};
            float shf[8] = {sh0.x, sh0.y, sh0.z, sh0.w, sh1.x, sh1.y, sh1.z, sh1.w};
            #pragma unroll
            for (int j = 0; j < 8; j++) {
                float v = b2f((u16)av[j]);
                v = fmaxf(v * scl[j] + shf[j], 0.f);
                av[j] = (short)f2b(v);
            }
        }
        #pragma unroll
        for (int nt = 0; nt < 4; nt++) {
            bf16x8 bv = *(const bf16x8*)(Wbase + (long)nt * 16 * K + kk);
            acc[nt] = __builtin_amdgcn_mfma_f32_16x16x32_bf16(av, bv, acc[nt], 0, 0, 0);
        }
    }
    u16* orow = out + row0 * HC;
    #pragma unroll
    for (int nt = 0; nt < 4; nt++) {
        #pragma unroll
        for (int j = 0; j < 4; j++) {
            int r = quad * 4 + j;
            int c = wave * 64 + nt * 16 + l15;
            orow[(long)r * HC + c] = f2b(acc[nt][j]);
        }
    }
}

// ---------------- a_s/a_d projection (+optional fused BN+ReLU on X) ----------------
template <int K, bool BN>
__global__ __launch_bounds__(256) void proj_att(const u16* __restrict__ X,
                                                const float* __restrict__ coef,
                                                const float* __restrict__ us,
                                                const float* __restrict__ ud,
                                                float* __restrict__ as_, float* __restrict__ ad_) {
    int wid = (blockIdx.x * 256 + threadIdx.x) >> 6;
    int lane = threadIdx.x & 63;
    if (wid >= NNODES) return;
    float pas[4] = {0.f, 0.f, 0.f, 0.f}, pad[4] = {0.f, 0.f, 0.f, 0.f};
    const u16* row = X + (long)wid * K;
    for (int f = lane; f < K; f += 64) {
        float xv = b2f(row[f]);
        if (BN) xv = fmaxf(xv * coef[f] + coef[256 + f], 0.f);
        #pragma unroll
        for (int h = 0; h < 4; h++) {
            pas[h] += xv * us[f * 4 + h];
            pad[h] += xv * ud[f * 4 + h];
        }
    }
    #pragma unroll
    for (int h = 0; h < 4; h++) {
        for (int o = 32; o; o >>= 1) {
            pas[h] += __shfl_down(pas[h], o);
            pad[h] += __shfl_down(pad[h], o);
        }
    }
    if (lane == 0) {
        #pragma unroll
        for (int h = 0; h < 4; h++) {
            as_[wid * 4 + h] = pas[h];
            ad_[wid * 4 + h] = pad[h];
        }
    }
}

// ---------------- fused GAT attention, one wave per dst node ----------------
__global__ __launch_bounds__(256) void gat_fused(
    const u16* __restrict__ xs, const float* __restrict__ as_, const float* __restrict__ ad_,
    const uint4* __restrict__ rec, int layer,
    const int* __restrict__ off, const int* __restrict__ deg,
    const u16* __restrict__ bias, u16* __restrict__ out) {
    __shared__ int s_lds[4][64];
    __shared__ float w_lds[4][64][4];
    int wid = (blockIdx.x * 256 + threadIdx.x) >> 6;
    if (wid >= NNODES) return;
    int wave = threadIdx.x >> 6;
    int lane = threadIdx.x & 63;
    int d = wid;
    int st = off[d], dg = deg[d];
    int slot = lane >> 2, h = lane & 3;
    float adv = ad_[d * 4 + h];
    float m = -1e30f, s = 0.f, sae = 0.f;
    const uint4* rbase = rec + (long)st * 2 + layer;

    if (dg <= 64) {
        // ---- phase 1 ----
        for (int i = slot; i < dg; i += 16) {
            uint4 r4 = rbase[(long)i * 2];
            int src = (int)r4.x;
            unsigned wsel = (h & 2) ? r4.z : r4.y;
            float aev = b2f((u16)((h & 1) ? (wsel >> 16) : (wsel & 0xffffu)));
            float t = as_[src * 4 + h] + adv + aev;
            float lg = (t > 0.f) ? t : 0.2f * t;
            if (h == 0) s_lds[wave][i] = src;
            w_lds[wave][i][h] = lg;
            sae += aev;
            float mn = fmaxf(m, lg);
            s = s * __expf(m - mn) + __expf(lg - mn);
            m = mn;
        }
        #pragma unroll
        for (int o = 4; o < 64; o <<= 1) {
            float mo = __shfl_xor(m, o), so = __shfl_xor(s, o), ao = __shfl_xor(sae, o);
            float mn = fmaxf(m, mo);
            s = s * __expf(m - mn) + so * __expf(mo - mn);
            m = mn;
            sae += ao;
        }
        float invs, wself;
        {
            float asv = as_[d * 4 + h];
            float l0 = asv + adv + sae / fmaxf((float)dg, 1.f);
            l0 = (l0 > 0.f) ? l0 : 0.2f * l0;
            float mn = fmaxf(m, l0);
            s = s * __expf(m - mn) + __expf(l0 - mn);
            m = mn;
            invs = 1.f / s;
            wself = __expf(l0 - mn) * invs;
        }
        for (int i = slot; i < dg; i += 16)
            w_lds[wave][i][h] = __expf(w_lds[wave][i][h] - m) * invs;

        // ---- phase 2: 32 lanes x uint4 cover the row; 8 edges in flight per wave ----
        int cg = lane & 31, half = lane >> 5;
        int ch8 = cg * 8;
        int h2 = cg >> 3;
        float ws2 = __shfl(wself, h2);
        const u16* xbase = xs + ch8;
        float a0, a1, a2, a3, a4, a5, a6, a7;
        {
            uint4 v = *(const uint4*)(xbase + (long)d * HC);
            float wsf = half ? 0.f : ws2;
            a0 = wsf * b2f((u16)(v.x & 0xffffu)); a1 = wsf * b2f((u16)(v.x >> 16));
            a2 = wsf * b2f((u16)(v.y & 0xffffu)); a3 = wsf * b2f((u16)(v.y >> 16));
            a4 = wsf * b2f((u16)(v.z & 0xffffu)); a5 = wsf * b2f((u16)(v.z >> 16));
            a6 = wsf * b2f((u16)(v.w & 0xffffu)); a7 = wsf * b2f((u16)(v.w >> 16));
        }
        int i = half;
        for (; i + 6 < dg; i += 8) {
            float wA = w_lds[wave][i][h2];     int sA = s_lds[wave][i];
            float wB = w_lds[wave][i + 2][h2]; int sB = s_lds[wave][i + 2];
            float wC = w_lds[wave][i + 4][h2]; int sC = s_lds[wave][i + 4];
            float wD = w_lds[wave][i + 6][h2]; int sD = s_lds[wave][i + 6];
            uint4 vA = *(const uint4*)(xbase + (long)sA * HC);
            uint4 vB = *(const uint4*)(xbase + (long)sB * HC);
            uint4 vC = *(const uint4*)(xbase + (long)sC * HC);
            uint4 vD = *(const uint4*)(xbase + (long)sD * HC);
            a0 += wA * b2f((u16)(vA.x & 0xffffu)) + wB * b2f((u16)(vB.x & 0xffffu))
                + wC * b2f((u16)(vC.x & 0xffffu)) + wD * b2f((u16)(vD.x & 0xffffu));
            a1 += wA * b2f((u16)(vA.x >> 16))     + wB * b2f((u16)(vB.x >> 16))
                + wC * b2f((u16)(vC.x >> 16))     + wD * b2f((u16)(vD.x >> 16));
            a2 += wA * b2f((u16)(vA.y & 0xffffu)) + wB * b2f((u16)(vB.y & 0xffffu))
                + wC * b2f((u16)(vC.y & 0xffffu)) + wD * b2f((u16)(vD.y & 0xffffu));
            a3 += wA * b2f((u16)(vA.y >> 16))     + wB * b2f((u16)(vB.y >> 16))
                + wC * b2f((u16)(vC.y >> 16))     + wD * b2f((u16)(vD.y >> 16));
            a4 += wA * b2f((u16)(vA.z & 0xffffu)) + wB * b2f((u16)(vB.z & 0xffffu))
                + wC * b2f((u16)(vC.z & 0xffffu)) + wD * b2f((u16)(vD.z & 0xffffu));
            a5 += wA * b2f((u16)(vA.z >> 16))     + wB * b2f((u16)(vB.z >> 16))
                + wC * b2f((u16)(vC.z >> 16))     + wD * b2f((u16)(vD.z >> 16));
            a6 += wA * b2f((u16)(vA.w & 0xffffu)) + wB * b2f((u16)(vB.w & 0xffffu))
                + wC * b2f((u16)(vC.w & 0xffffu)) + wD * b2f((u16)(vD.w & 0xffffu));
            a7 += wA * b2f((u16)(vA.w >> 16))     + wB * b2f((u16)(vB.w >> 16))
                + wC * b2f((u16)(vC.w >> 16))     + wD * b2f((u16)(vD.w >> 16));
        }
        for (; i < dg; i += 2) {
            float wA = w_lds[wave][i][h2]; int sA = s_lds[wave][i];
            uint4 vA = *(const uint4*)(xbase + (long)sA * HC);
            a0 += wA * b2f((u16)(vA.x & 0xffffu)); a1 += wA * b2f((u16)(vA.x >> 16));
            a2 += wA * b2f((u16)(vA.y & 0xffffu)); a3 += wA * b2f((u16)(vA.y >> 16));
            a4 += wA * b2f((u16)(vA.z & 0xffffu)); a5 += wA * b2f((u16)(vA.z >> 16));
            a6 += wA * b2f((u16)(vA.w & 0xffffu)); a7 += wA * b2f((u16)(vA.w >> 16));
        }
        a0 += __shfl_xor(a0, 32); a1 += __shfl_xor(a1, 32);
        a2 += __shfl_xor(a2, 32); a3 += __shfl_xor(a3, 32);
        a4 += __shfl_xor(a4, 32); a5 += __shfl_xor(a5, 32);
        a6 += __shfl_xor(a6, 32); a7 += __shfl_xor(a7, 32);
        if (half == 0) {
            uint4 bv = *(const uint4*)(bias + ch8);
            a0 += b2f((u16)(bv.x & 0xffffu)); a1 += b2f((u16)(bv.x >> 16));
            a2 += b2f((u16)(bv.y & 0xffffu)); a3 += b2f((u16)(bv.y >> 16));
            a4 += b2f((u16)(bv.z & 0xffffu)); a5 += b2f((u16)(bv.z >> 16));
            a6 += b2f((u16)(bv.w & 0xffffu)); a7 += b2f((u16)(bv.w >> 16));
            uint4 ov;
            ov.x = (unsigned)f2b(a0) | ((unsigned)f2b(a1) << 16);
            ov.y = (unsigned)f2b(a2) | ((unsigned)f2b(a3) << 16);
            ov.z = (unsigned)f2b(a4) | ((unsigned)f2b(a5) << 16);
            ov.w = (unsigned)f2b(a6) | ((unsigned)f2b(a7) << 16);
            *(uint4*)(out + (long)d * HC + ch8) = ov;
        }
        return;
    }

    // ---------- fallback path (deg > 64): exact ----------
    for (int base = 0; base < dg; base += 16) {
        int i = base + slot;
        float lg = -1e30f, aev = 0.f, w = 0.f;
        if (i < dg) {
            uint4 r4 = rbase[(long)i * 2];
            int src = (int)r4.x;
            unsigned wsel = (h & 2) ? r4.z : r4.y;
            aev = b2f((u16)((h & 1) ? (wsel >> 16) : (wsel & 0xffffu)));
            float t = as_[src * 4 + h] + adv + aev;
            lg = (t > 0.f) ? t : 0.2f * t;
        }
        sae += aev;
        float mn = fmaxf(m, lg);
        if (i < dg) w = __expf(lg - mn);
        s = s * __expf(m - mn) + w;
        m = mn;
    }
    #pragma unroll
    for (int o = 4; o < 64; o <<= 1) {
        float mo = __shfl_xor(m, o), so = __shfl_xor(s, o), ao = __shfl_xor(sae, o);
        float mn = fmaxf(m, mo);
        s = s * __expf(m - mn) + so * __expf(mo - mn);
        m = mn;
        sae += ao;
    }
    float invs, wself;
    {
        float asv = as_[d * 4 + h];
        float l0 = asv + adv + sae / fmaxf((float)dg, 1.f);
        l0 = (l0 > 0.f) ? l0 : 0.2f * l0;
        float mn = fmaxf(m, l0);
        s = s * __expf(m - mn) + __expf(l0 - mn);
        m = mn;
        invs = 1.f / s;
        wself = __expf(l0 - mn) * invs;
    }
    int h2 = lane >> 4;
    float m2 = __shfl(m, h2);
    float is2 = __shfl(invs, h2);
    float ws2 = __shfl(wself, h2);
    float adv2 = __shfl(adv, h2);
    int cb = lane * 4;
    float a0, a1, a2, a3;
    {
        uint2 v = *(const uint2*)(xs + (long)d * HC + cb);
        a0 = ws2 * b2f((u16)(v.x & 0xffffu)); a1 = ws2 * b2f((u16)(v.x >> 16));
        a2 = ws2 * b2f((u16)(v.y & 0xffffu)); a3 = ws2 * b2f((u16)(v.y >> 16));
    }
    int slot16 = lane & 15;
    int lhi = lane & 48;
    for (int base = 0; base < dg; base += 16) {
        int cnt = min(16, dg - base);
        float wv = 0.f;
        int srcl = 0;
        if (slot16 < cnt) {
            uint4 r4 = rbase[(long)(base + slot16) * 2];
            srcl = (int)r4.x;
            unsigned wsel = (h2 & 2) ? r4.z : r4.y;
            float aev = b2f((u16)((h2 & 1) ? (wsel >> 16) : (wsel & 0xffffu)));
            float t = as_[srcl * 4 + h2] + adv2 + aev;
            t = (t > 0.f) ? t : 0.2f * t;
            wv = __expf(t - m2) * is2;
        }
        for (int j = 0; j < cnt; j++) {
            float w0 = __shfl(wv, lhi | j);
            int s0 = __shfl(srcl, j);
            uint2 v0 = *(const uint2*)(xs + (long)s0 * HC + cb);
            a0 += w0 * b2f((u16)(v0.x & 0xffffu));
            a1 += w0 * b2f((u16)(v0.x >> 16));
            a2 += w0 * b2f((u16)(v0.y & 0xffffu));
            a3 += w0 * b2f((u16)(v0.y >> 16));
        }
    }
    u16 o0 = f2b(a0 + b2f(bias[cb + 0]));
    u16 o1 = f2b(a1 + b2f(bias[cb + 1]));
    u16 o2 = f2b(a2 + b2f(bias[cb + 2]));
    u16 o3 = f2b(a3 + b2f(bias[cb + 3]));
    uint2 ov;
    ov.x = (unsigned)o0 | ((unsigned)o1 << 16);
    ov.y = (unsigned)o2 | ((unsigned)o3 << 16);
    *(uint2*)(out + (long)d * HC + cb) = ov;
}

// ---------------- BatchNorm stats ----------------
__global__ void bn_stats(const u16* __restrict__ h, float* __restrict__ stats) {
    int c = threadIdx.x;
    float s = 0.f, q = 0.f;
    for (int r = blockIdx.x; r < NNODES; r += gridDim.x) {
        float v = b2f(h[(long)r * HC + c]);
        s += v;
        q += v * v;
    }
    atomicAdd(&stats[c], s);
    atomicAdd(&stats[256 + c], q);
}

// ---------------- output head (+fused BN2+ReLU) ----------------
__global__ __launch_bounds__(256) void out_head(const u16* __restrict__ h,
                                                const float* __restrict__ coef,
                                                const u16* __restrict__ wout,
                                                const u16* __restrict__ bout,
                                                void* __restrict__ y,
                                                const int* __restrict__ flag) {
    int wid = (blockIdx.x * 256 + threadIdx.x) >> 6;
    int lane = threadIdx.x & 63;
    if (wid >= NNODES) return;
    const u16* r = h + (long)wid * HC + lane * 4;
    int c0 = lane * 4;
    float p = 0.f;
    #pragma unroll
    for (int j = 0; j < 4; j++) {
        float v = b2f(r[j]);
        v = fmaxf(v * coef[c0 + j] + coef[256 + c0 + j], 0.f);
        p += v * b2f(wout[c0 + j]);
    }
    for (int o = 32; o; o >>= 1) p += __shfl_down(p, o);
    if (lane == 0) {
        float v = p + b2f(bout[0]);
        if (*flag) ((u16*)y)[wid] = f2b(v);
        else       ((float*)y)[wid] = v;
    }
}

extern "C" void kernel_launch(void* const* d_in, const int* in_sizes, int n_in,
                              void* d_out, int out_size, void* d_ws, size_t ws_size,
                              hipStream_t stream) {
    (void)in_sizes; (void)n_in; (void)out_size; (void)ws_size;
    const void* x_raw     = d_in[0];
    const int*  esrc      = (const int*)d_in[1];
    const int*  edst      = (const int*)d_in[2];
    const void* eattr_raw = d_in[3];

    char* ws = (char*)d_ws;
    size_t o = 0;
    auto alloc = [&](size_t bytes) -> char* {
        o = (o + 255) & ~(size_t)255;
        char* p = ws + o;
        o += bytes;
        return p;
    };
    int* dflag = (int*)alloc(256);
    u16* xb   = (u16*)alloc((size_t)NNODES * 64 * 2);
    u16* pall = (u16*)alloc((size_t)TOTP * 2);
    u16 *W1b = pall + hPO[0], *atts1b = pall + hPO[1], *attd1b = pall + hPO[2],
        *We1b = pall + hPO[3], *atte1b = pall + hPO[4], *b1b = pall + hPO[5],
        *g1b = pall + hPO[6], *be1b = pall + hPO[7], *W2b = pall + hPO[8],
        *atts2b = pall + hPO[9], *attd2b = pall + hPO[10], *We2b = pall + hPO[11],
        *atte2b = pall + hPO[12], *b2b = pall + hPO[13], *g2b = pall + hPO[14],
        *be2b = pall + hPO[15], *Woutb = pall + hPO[16], *boutb = pall + hPO[17];
    u16* WT1 = (u16*)alloc(256 * 64 * 2);
    u16* WT2 = (u16*)alloc(256 * 256 * 2);
    float* ve1 = (float*)alloc(64 * 4);
    float* ve2 = (float*)alloc(64 * 4);
    float* us1 = (float*)alloc(256 * 4);
    float* ud1 = (float*)alloc(256 * 4);
    float* us2 = (float*)alloc(1024 * 4);
    float* ud2 = (float*)alloc(1024 * 4);
    float* coef1 = (float*)alloc(512 * 4);
    float* coef2 = (float*)alloc(512 * 4);
    // zero zone: deg + stats
    int* deg = (int*)alloc((size_t)NNODES * 4);
    float* stats1 = (float*)alloc(512 * 4);
    float* stats2 = (float*)alloc(512 * 4);
    size_t zero_end = o;
    size_t zero_begin = (size_t)((char*)deg - ws);
    // rest
    int* off = (int*)alloc((size_t)NNODES * 4);
    int* cursor = (int*)alloc((size_t)NNODES * 4);
    int* bsums = (int*)alloc(256 * 4);
    int* boffs = (int*)alloc(256 * 4);
    uint4* rec = (uint4*)alloc((size_t)NEDGES * 32);
    float* as_ = (float*)alloc((size_t)NNODES * 16);
    float* ad_ = (float*)alloc((size_t)NNODES * 16);
    u16* bufA = (u16*)alloc((size_t)NNODES * HC * 2);  // xs1, then xs2
    u16* bufB = (u16*)alloc((size_t)NNODES * HC * 2);  // h1raw, then h2raw

    long zwords = (long)((zero_end - zero_begin) / 4);
    zero_init<<<128, 256, 0, stream>>>((unsigned*)(ws + zero_begin), zwords);
    detect_dtype<<<1, 256, 0, stream>>>((const unsigned*)x_raw, dflag);

    cvt_bf16<<<2048, 256, 0, stream>>>(x_raw, xb, NNODES * 64, dflag);
    Ptrs18 pp;
    for (int i = 0; i < 18; i++) pp.s[i] = d_in[4 + i];
    cvt_params<<<(TOTP + 255) / 256, 256, 0, stream>>>(pp, pall, dflag);

    transpose_w<<<64, 256, 0, stream>>>(W1b, WT1, 64);
    transpose_w<<<256, 256, 0, stream>>>(W2b, WT2, 256);
    proj_weight<<<1, 256, 0, stream>>>(We1b, atte1b, ve1, 16);
    proj_weight<<<1, 256, 0, stream>>>(We2b, atte2b, ve2, 16);
    proj_weight2<<<1, 256, 0, stream>>>(W1b, atts1b, attd1b, us1, ud1, 64);
    proj_weight2<<<4, 256, 0, stream>>>(W2b, atts2b, attd2b, us2, ud2, 256);

    int eblocks = (NEDGES + 255) / 256;
    int nb = (NNODES + 255) / 256;  // 196
    edge_deg<<<eblocks, 256, 0, stream>>>(edst, deg);
    block_sum<<<nb, 256, 0, stream>>>(deg, bsums, NNODES);
    scan_bsums<<<1, 256, 0, stream>>>(bsums, boffs, nb);
    write_offsets<<<nb, 256, 0, stream>>>(deg, boffs, off, cursor, NNODES);
    edge_stage<<<eblocks, 256, 0, stream>>>(eattr_raw, dflag, esrc, edst, ve1, ve2,
                                            cursor, rec);

    int mtiles = NNODES / 16;                 // 3125
    int wblocks = (NNODES * 64 + 255) / 256;  // 12500

    // layer 1 (xb: K=64, no BN on input)
    gemm_mfma<64, false><<<mtiles, 256, 0, stream>>>(xb, WT1, nullptr, bufA);
    proj_att<64, false><<<wblocks, 256, 0, stream>>>(xb, nullptr, us1, ud1, as_, ad_);
    gat_fused<<<wblocks, 256, 0, stream>>>(bufA, as_, ad_, rec, 0, off, deg, b1b, bufB);
    bn_stats<<<512, 256, 0, stream>>>(bufB, stats1);
    bn_coef<<<1, 256, 0, stream>>>(stats1, g1b, be1b, coef1);

    // layer 2 (h1raw = bufB, BN1 fused into consumers)
    gemm_mfma<256, true><<<mtiles, 256, 0, stream>>>(bufB, WT2, coef1, bufA);
    proj_att<256, true><<<wblocks, 256, 0, stream>>>(bufB, coef1, us2, ud2, as_, ad_);
    gat_fused<<<wblocks, 256, 0, stream>>>(bufA, as_, ad_, rec, 1, off, deg, b2b, bufB);
    bn_stats<<<512, 256, 0, stream>>>(bufB, stats2);
    bn_coef<<<1, 256, 0, stream>>>(stats2, g2b, be2b, coef2);

    // output head (BN2 fused)
    out_head<<<wblocks, 256, 0, stream>>>(bufB, coef2, Woutb, boutb, d_out, dflag);
}